// Round 12
// baseline (146.643 us; speedup 1.0000x reference)
//
#include <hip/hip_runtime.h>
#include <hip/hip_bf16.h>
#include <math.h>

#define BATCH  128
#define CIN    256
#define HWSZ   1024
#define NATT   64
#define TRI    2080
#define PLANES 256

typedef __attribute__((ext_vector_type(8))) short short8v;
typedef __attribute__((ext_vector_type(4))) float f32x4;

// ---------------- workspace layout (float slots) ----------------
static const size_t WHI_OFF   = 0;         // uint [64][128]       8192
static const size_t WLO_OFF   = 8192;      // uint [64][128]       8192
static const size_t GATE_OFF  = 16384;     // [128][256]           32768
static const size_t PSUM_OFF  = 49152;     // [512][64]            32768
static const size_t PGRAM_OFF = 81920;     // [512][64][64]        2097152
static const size_t VEC_OFF   = 2179072;   // [128][2080]          266240

// ---------------- helpers ----------------
__device__ __forceinline__ unsigned int pk2(float a, float b){
  union { __hip_bfloat16 h; unsigned short u; } A, B;
  A.h = __float2bfloat16(a); B.h = __float2bfloat16(b);
  return (unsigned int)A.u | ((unsigned int)B.u << 16);
}
__device__ __forceinline__ unsigned int pack_hl(float v){
  unsigned int b  = __float_as_uint(v);
  unsigned int hb = b >> 16;
  float hif = __uint_as_float(hb << 16);
  float lo  = v - hif;
  unsigned int lb = __float_as_uint(lo) >> 16;
  return hb | (lb << 16);
}
union U4S8 { uint4 u; short8v s; };
__device__ __forceinline__ short8v bc8(uint4 v){ U4S8 x; x.u = v; return x.s; }

// v_perm unpack for the hi/lo packed NS matrices
__device__ __forceinline__ void unpack8p(const unsigned int* w, short8v& h, short8v& l){
  union { unsigned int u[4]; short8v s; } H, L;
#pragma unroll
  for (int i=0;i<4;i++){
    H.u[i] = __builtin_amdgcn_perm(w[2*i+1], w[2*i], 0x05040100u);
    L.u[i] = __builtin_amdgcn_perm(w[2*i+1], w[2*i], 0x07060302u);
  }
  h = H.s; l = L.s;
}
__device__ __forceinline__ void unpack8v(uint4 a, uint4 b, short8v& h, short8v& l){
  unsigned int w[8] = {a.x,a.y,a.z,a.w,b.x,b.y,b.z,b.w};
  unpack8p(w, h, l);
}

// ---------------- kernel 0: pack conv_w to bf16 hi/lo PAIR arrays ----------------
__global__ void k_pack_w2(const float* __restrict__ w,
                          unsigned int* __restrict__ whi, unsigned int* __restrict__ wlo){
  int idx = blockIdx.x*256 + threadIdx.x;       // uint index: o*128 + u
  if (idx < 64*128){
    float w0 = w[2*idx], w1 = w[2*idx+1];
    unsigned int h0 = __float_as_uint(w0)>>16, h1 = __float_as_uint(w1)>>16;
    float l0f = w0 - __uint_as_float(h0<<16);
    float l1f = w1 - __uint_as_float(h1<<16);
    whi[idx] = h0 | (h1<<16);
    wlo[idx] = (__float_as_uint(l0f)>>16) | ((__float_as_uint(l1f)>>16)<<16);
  }
}

// ---------------- kernel 1: fused conv+BN+ReLU+gram, WAVE-AUTONOMOUS conv ------
// grid: 128 b x 4 quarters (256 px) = 512 blocks, 512 threads (8 waves).
// Each wave: 32-px strip x 64 outputs; x staged via PRIVATE LDS dbuf region
// (coalesced float4 loads -> shfl channel-pair -> bf16 transpose write ->
//  b64 frag reads). ZERO barriers in K-loop; waves drift freely (TLP hiding).
// After one barrier: yt (aliases pool) + psum + gram (R10-proven epilogue).
#define WST 18      // LDS row stride (uints): 72B = b64-aligned, 2-way banks
__global__ __launch_bounds__(512, 4) void k_conv_gram(
    const float* __restrict__ x,
    const unsigned int* __restrict__ whi, const unsigned int* __restrict__ wlo,
    const float* __restrict__ gam, const float* __restrict__ bet,
    const float* __restrict__ mu,  const float* __restrict__ var,
    float* __restrict__ pgram, float* __restrict__ psum){
  __shared__ __align__(16) unsigned int pool[8*2*32*WST];   // 36864 B
  __shared__ float scl[64], shf[64];
  int tid = threadIdx.x, l = tid & 63, w = tid >> 6;
  int i15 = l & 15, q = l >> 4;
  int bid = blockIdx.x, b = bid >> 2, sg = bid & 3;
  if (tid < 64){
    float sc = gam[tid]*rsqrtf(var[tid]+1e-5f);
    scl[tid] = sc; shf[tid] = bet[tid] - mu[tid]*sc;
  }
  unsigned int* xsw = pool + w*(2*32*WST);      // wave-private region
  const float* xb = x + (size_t)b*CIN*HWSZ + sg*256 + w*32;
  int lc  = l >> 3;                              // 0..7 channel sub-index
  int px4 = (l & 7) * 4;                         // pixel base (within strip)
  bool wr = ((lc & 1) == 0);                     // even-channel lanes write
  int cpb = (l >> 4);                            // cp base for writes

  f32x4 acc[4][2];
#pragma unroll
  for (int ot=0;ot<4;ot++){ acc[ot][0]=(f32x4){0,0,0,0}; acc[ot][1]=(f32x4){0,0,0,0}; }
  float4 vv[2][4];

#define LOADT(S, T) { _Pragma("unroll") \
  for (int k=0;k<4;k++) vv[S][k] = *(const float4*)(xb + (size_t)((T)*32 + lc + 8*k)*HWSZ + px4); }
#define PWRITE(S, BUF) { _Pragma("unroll") \
  for (int k=0;k<4;k++){ \
    float4 v = vv[S][k]; \
    float nx = __shfl_down(v.x,8), ny = __shfl_down(v.y,8); \
    float nz = __shfl_down(v.z,8), nw = __shfl_down(v.w,8); \
    if (wr){ \
      unsigned int* r = xsw + ((BUF)*32 + px4)*WST + cpb + 4*k; \
      r[0*WST] = pk2(v.x,nx); r[1*WST] = pk2(v.y,ny); \
      r[2*WST] = pk2(v.z,nz); r[3*WST] = pk2(v.w,nw); } } }

  // prologue: tile0 -> buf0; tile1 -> regs
  LOADT(0, 0)
  PWRITE(0, 0)
  LOADT(1, 1)

#pragma unroll
  for (int s=0; s<8; ++s){
    // frag reads from buf s&1 (b64-aligned rows)
    const unsigned int* r0 = xsw + ((s&1)*32 + i15)*WST + q*4;
    const unsigned int* r1 = r0 + 16*WST;
    uint2 a0 = *(const uint2*)r0,  a1 = *(const uint2*)(r0+2);
    uint2 c0 = *(const uint2*)r1,  c1 = *(const uint2*)(r1+2);
    uint4 bf0 = {a0.x, a0.y, a1.x, a1.y};
    uint4 bf1 = {c0.x, c0.y, c1.x, c1.y};
    if (s < 7){ if (s & 1) { PWRITE(0, 0) } else { PWRITE(1, 1) } }   // tile s+1
    if (s < 6){ if (s & 1) { LOADT(1, s+2) } else { LOADT(0, s+2) } } // tile s+2
#pragma unroll
    for (int ot=0; ot<4; ++ot){
      uint4 ahi = *(const uint4*)(whi + (ot*16+i15)*128 + s*16 + q*4);
      uint4 alo = *(const uint4*)(wlo + (ot*16+i15)*128 + s*16 + q*4);
      acc[ot][0] = __builtin_amdgcn_mfma_f32_16x16x32_bf16(bc8(ahi), bc8(bf0), acc[ot][0],0,0,0);
      acc[ot][0] = __builtin_amdgcn_mfma_f32_16x16x32_bf16(bc8(alo), bc8(bf0), acc[ot][0],0,0,0);
      acc[ot][1] = __builtin_amdgcn_mfma_f32_16x16x32_bf16(bc8(ahi), bc8(bf1), acc[ot][1],0,0,0);
      acc[ot][1] = __builtin_amdgcn_mfma_f32_16x16x32_bf16(bc8(alo), bc8(bf1), acc[ot][1],0,0,0);
    }
  }
#undef LOADT
#undef PWRITE

  __syncthreads();                               // all waves done; pool becomes yt
  unsigned int (*yt)[132] = (unsigned int (*)[132])pool;
  // epilogue: BN + ReLU, pack px-pairs -> yt (wave-private column range)
#pragma unroll
  for (int ot=0; ot<4; ++ot)
#pragma unroll
    for (int pt=0; pt<2; ++pt)
#pragma unroll
      for (int r=0; r<4; ++r){
        int o = ot*16 + q*4 + r;
        float v = fmaf(acc[ot][pt][r], scl[o], shf[o]);
        v = v>0.f ? v : 0.f;
        float nb = __shfl_xor(v, 1);
        if (!(i15 & 1)) yt[o][w*16 + pt*8 + (i15>>1)] = pk2(v, nb);
      }
  __syncthreads();
  // psum: row sums over 256 px (8 threads per row)
  {
    int row = tid >> 3, seg = tid & 7;
    float s = 0.f;
#pragma unroll
    for (int m=0; m<16; ++m){
      unsigned int u = yt[row][seg*16 + m];
      s += __uint_as_float(u<<16) + __uint_as_float(u & 0xffff0000u);
    }
    s += __shfl_down(s, 4, 8);
    s += __shfl_down(s, 2, 8);
    s += __shfl_down(s, 1, 8);
    if (seg == 0) psum[(size_t)bid*64 + row] = s;
  }
  // gram = Y Y^T over 256 px: wave -> tiles (ti, tj0), (ti, tj0+1)
  {
    f32x4 g0 = (f32x4){0.f,0.f,0.f,0.f}, g1 = g0;
    int ti = w >> 1, tj0 = (w & 1) * 2;
#pragma unroll
    for (int ks=0; ks<8; ks++){
      int ku = ks*16 + q*4;
      uint4 a  = *(const uint4*)&yt[ti*16      + i15][ku];
      uint4 b0 = *(const uint4*)&yt[tj0*16     + i15][ku];
      uint4 b1 = *(const uint4*)&yt[(tj0+1)*16 + i15][ku];
      g0 = __builtin_amdgcn_mfma_f32_16x16x32_bf16(bc8(a), bc8(b0), g0,0,0,0);
      g1 = __builtin_amdgcn_mfma_f32_16x16x32_bf16(bc8(a), bc8(b1), g1,0,0,0);
    }
    float* pg = pgram + (size_t)bid*4096;
#pragma unroll
    for (int r=0;r<4;r++){
      int i = ti*16 + q*4 + r;
      pg[i*64 + tj0*16     + i15] = g0[r];
      pg[i*64 + (tj0+1)*16 + i15] = g1[r];
    }
  }
}

// P = L @ R for 64x64 packed hi/lo (R symmetric: B-frags read row-wise).
__device__ __forceinline__ void wave_mm(const unsigned int (*PL)[68],
                                        const unsigned int (*PR)[68],
                                        int lane, int rp, int ch, f32x4* acc){
  f32x4 z = {0.f,0.f,0.f,0.f};
  acc[0] = z; acc[1] = z;
  int i15 = lane & 15, q = lane >> 4;
  int row = rp*16 + i15;
#pragma unroll
  for (int s=0; s<2; s++){
    int kbase = s*32 + (q<<3);
    uint4 a0 = *(const uint4*)&PL[row][kbase];
    uint4 a1 = *(const uint4*)&PL[row][kbase+4];
    short8v ah, al; unpack8v(a0,a1,ah,al);
#pragma unroll
    for (int ct=0; ct<2; ct++){
      const unsigned int* bp = &PR[ch*32 + ct*16 + i15][kbase];
      uint4 b0 = *(const uint4*)bp;
      uint4 b1 = *(const uint4*)(bp+4);
      short8v bh, bl; unpack8v(b0,b1,bh,bl);
      acc[ct] = __builtin_amdgcn_mfma_f32_16x16x32_bf16(ah, bh, acc[ct], 0,0,0);
      acc[ct] = __builtin_amdgcn_mfma_f32_16x16x32_bf16(ah, bl, acc[ct], 0,0,0);
      acc[ct] = __builtin_amdgcn_mfma_f32_16x16x32_bf16(al, bh, acc[ct], 0,0,0);
    }
  }
}

template<int MODE>  // 0: pack(v)  1: pack(0.5*(3I-v))  2: pack(3I-v)
__device__ __forceinline__ void store_packed(unsigned int (*PD)[68], const f32x4* acc,
                                             int lane, int rp, int ch){
  int i15 = lane & 15, q = lane >> 4;
#pragma unroll
  for (int ct=0; ct<2; ct++){
    int col = ch*32 + ct*16 + i15;
#pragma unroll
    for (int r=0; r<4; r++){
      int row = rp*16 + q*4 + r;
      float v = acc[ct][r];
      if (MODE==1) v = 0.5f*((row==col?3.f:0.f) - v);
      if (MODE==2) v = (row==col?3.f:0.f) - v;
      PD[row][col] = pack_hl(v);
    }
  }
}

// ---------------- kernel 2: Newton-Schulz + triuvec -> vec ----------------
__global__ __launch_bounds__(512) void k_ns(const float* __restrict__ pgram,
    const float* __restrict__ psum, float* __restrict__ vecg){
  __shared__ float Af[64][68];
  __shared__ unsigned int PA[64][68];
  __shared__ unsigned int PT[64][68];
  __shared__ unsigned int PY[64][68];
  __shared__ unsigned int PZ[64][68];
  __shared__ float meanl[64];
  __shared__ float snorm;
  int b = blockIdx.x, tid = threadIdx.x;
  int lane = tid & 63, wv = tid >> 6, rp = wv & 3, ch = wv >> 2;
  const float* pc0 = pgram + ((size_t)b*4) * (NATT*NATT);
  if (tid < 64){
    const float* ps = psum + (size_t)b*256;
    float s = 0.f;
#pragma unroll
    for (int k=0;k<4;k++) s += ps[64*k + tid];
    meanl[tid] = s * (1.f/1024.f);
  }
  __syncthreads();
  for (int e=tid; e<4096; e+=512){
    int i = e>>6, j = e&63;
    float s = 0.f;
#pragma unroll
    for (int k=0;k<4;k++) s += pc0[4096*k + e];
    Af[i][j] = s * (1.f/1024.f) - meanl[i]*meanl[j];
  }
  __syncthreads();
  if (tid < 64){
    float s = Af[tid][tid];
#pragma unroll
    for (int off=32; off; off>>=1) s += __shfl_down(s, off);
    if (tid==0) snorm = s;
  }
  __syncthreads();
  float normA = snorm;
  float inv = 1.f/normA;
  for (int e=tid; e<4096; e+=512){
    int i = e>>6, j = e&63;
    float an = Af[i][j]*inv;
    float t  = 0.5f*((i==j?3.f:0.f) - an);
    unsigned int pt = pack_hl(t);
    PA[i][j] = pack_hl(an);
    PT[i][j] = pt;
    PZ[i][j] = pt;
  }
  __syncthreads();

  f32x4 accY[2], accZ[2];
  wave_mm(PA, PT, lane, rp, ch, accY);
  store_packed<0>(PY, accY, lane, rp, ch);
  __syncthreads();

  for (int it=0; it<3; ++it){
    wave_mm(PZ, PY, lane, rp, ch, accY);
    store_packed<1>(PT, accY, lane, rp, ch);
    __syncthreads();
    wave_mm(PY, PT, lane, rp, ch, accY);
    wave_mm(PT, PZ, lane, rp, ch, accZ);
    __syncthreads();
    store_packed<0>(PY, accY, lane, rp, ch);
    store_packed<0>(PZ, accZ, lane, rp, ch);
    __syncthreads();
  }
  wave_mm(PZ, PY, lane, rp, ch, accY);
  store_packed<2>(PT, accY, lane, rp, ch);
  __syncthreads();
  wave_mm(PY, PT, lane, rp, ch, accY);
  float scl = 0.5f * sqrtf(normA);
  {
    int i15 = lane & 15, q = lane >> 4;
#pragma unroll
    for (int ct=0; ct<2; ct++){
      int col = ch*32 + ct*16 + i15;
#pragma unroll
      for (int r=0; r<4; r++){
        int row = rp*16 + q*4 + r;
        Af[row][col] = accY[ct][r]*scl;
      }
    }
  }
  __syncthreads();
  float* vp = vecg + (size_t)b*TRI;
  for (int e=tid; e<4096; e+=512){
    int i = e>>6, j = e&63;
    if (j >= i){
      int t0 = (i*(129 - i)) >> 1;
      vp[t0 + j - i] = Af[i][j];
    }
  }
}

// ---------------- kernel 3: FC + sigmoid ----------------
__global__ __launch_bounds__(512) void k_fc(const float* __restrict__ vecg,
    const float* __restrict__ fcw, const float* __restrict__ fcb,
    float* __restrict__ gate){
  __shared__ float fwL[16][2080];
  __shared__ __align__(16) float vecL[2080];
  int bg = blockIdx.x >> 4, pg = blockIdx.x & 15;
  int tid = threadIdx.x;
  for (int i=tid; i<8320; i+=512){
    int row = i/520, c4 = i - row*520;
    *(float4*)&fwL[row][c4<<2] = *(const float4*)(fcw + (size_t)(pg*16+row)*TRI + (c4<<2));
  }
  int p = tid >> 5, s = tid & 31;
  int base = s*65;
  float bias = fcb[pg*16 + p];
  for (int bi=0; bi<16; ++bi){
    int b = bg*16 + bi;
    __syncthreads();
    for (int i=tid; i<520; i+=512)
      *(float4*)&vecL[i<<2] = *(const float4*)(vecg + (size_t)b*TRI + (i<<2));
    __syncthreads();
    float acc = 0.f;
#pragma unroll 13
    for (int m=0; m<65; ++m)
      acc = fmaf(fwL[p][base+m], vecL[base+m], acc);
    acc += __shfl_down(acc, 16, 32);
    acc += __shfl_down(acc, 8, 32);
    acc += __shfl_down(acc, 4, 32);
    acc += __shfl_down(acc, 2, 32);
    acc += __shfl_down(acc, 1, 32);
    if (s==0)
      gate[(size_t)b*PLANES + pg*16 + p] = 1.f/(1.f + expf(-(acc + bias)));
  }
}

// ---------------- kernel 4: out = x * gate[b,c] ----------------
__global__ __launch_bounds__(256) void k_gate_mul(const float* __restrict__ x,
    const float* __restrict__ gate, float* __restrict__ out){
  size_t base = (size_t)blockIdx.x*256 + threadIdx.x;
#pragma unroll
  for (int k=0;k<8;k++){
    size_t i4 = base + (size_t)k*1048576;
    size_t e  = i4 << 2;
    int bc = (int)(e >> 10);
    float g = gate[bc];
    float4 v = *(const float4*)(x + e);
    v.x *= g; v.y *= g; v.z *= g; v.w *= g;
    *(float4*)(out + e) = v;
  }
}

extern "C" void kernel_launch(void* const* d_in, const int* in_sizes, int n_in,
                              void* d_out, int out_size, void* d_ws, size_t ws_size,
                              hipStream_t stream) {
  const float* x    = (const float*)d_in[0];
  const float* cw   = (const float*)d_in[1];
  const float* gam  = (const float*)d_in[2];
  const float* bet  = (const float*)d_in[3];
  const float* mu   = (const float*)d_in[4];
  const float* var  = (const float*)d_in[5];
  const float* fcw  = (const float*)d_in[6];
  const float* fcb  = (const float*)d_in[7];
  float* out = (float*)d_out;
  float* ws  = (float*)d_ws;

  unsigned int* whi = (unsigned int*)(ws + WHI_OFF);
  unsigned int* wlo = (unsigned int*)(ws + WLO_OFF);
  float* gate  = ws + GATE_OFF;
  float* psum  = ws + PSUM_OFF;
  float* pgram = ws + PGRAM_OFF;
  float* vecg  = ws + VEC_OFF;

  k_pack_w2<<<32, 256, 0, stream>>>(cw, whi, wlo);
  k_conv_gram<<<BATCH*4, 512, 0, stream>>>(x, whi, wlo, gam, bet, mu, var, pgram, psum);
  k_ns<<<BATCH, 512, 0, stream>>>(pgram, psum, vecg);
  k_fc<<<128, 512, 0, stream>>>(vecg, fcw, fcb, gate);
  k_gate_mul<<<4096, 256, 0, stream>>>(x, gate, out);
}